// Round 9
// baseline (254.008 us; speedup 1.0000x reference)
//
#include <hip/hip_runtime.h>
#include <hip/hip_fp16.h>

// NNConv on MI355X. msg[E x 32] = Z[E x 4096] @ w2r[4096 x 32],
// Z[e, c*32+i] = h[e,c]*xs[e,i] built on the fly in fp16 A-fragments.
// Round 19: REGISTER-RESIDENT h. R17's proven skeleton (2-wave blocks,
// grid 1563, live-guard, linear columns, 4-deep B reg buffers, 2
// launches) with ONE change: the per-column LDS round-trip for d
// (ds_write in phase1 + ds_read_b64 + ~120cy lgkmcnt per column = the
// ~350 idle cy/col identified in R13-R17) is replaced by phase1 packing
// h into hpk[4][8] regs and, per even-q, 8 permlane32_swap ops filling
// a 16-reg Ac/Yc cache (half<->half exchange, pure VALU, no wait).
// R18's NaN is attributed to the hand-rolled tied-operand inline asm;
// this uses the guide-verified __builtin_amdgcn_permlane32_swap (with
// an orientation-safe __shfl_xor fallback). LDS = 0.
// __launch_bounds__(128,1): empirical law cap = 512/(1*2) = 256 VGPR.

#define NN 25000
#define EE 400000

typedef _Float16 f16x8 __attribute__((ext_vector_type(8)));
typedef float    f32x16 __attribute__((ext_vector_type(16)));
typedef unsigned u32x2  __attribute__((ext_vector_type(2)));

// half-exchange: a = half0-lane values (rows base,base+1), y = half1-lane
// values (rows base+4,base+5), for every lane's own edge column (l&31).
__device__ __forceinline__ void swapHalves(unsigned u, int half,
                                           unsigned& a, unsigned& y) {
#if __has_builtin(__builtin_amdgcn_permlane32_swap)
    u32x2 rr = __builtin_amdgcn_permlane32_swap(u, u, false, false);
    a = rr.x;              // vdst: upper lanes replaced by vsrc lower = lane(l&31)
    y = rr.y;              // vsrc: lower lanes replaced by vdst upper = lane((l&31)+32)
#else
    unsigned p = (unsigned)__shfl_xor((int)u, 32, 64);
    a = half ? p : u;
    y = half ? u : p;
#endif
}

// ---------------- launch 1: pack w1/w2/b2 + out = x@root + bias ----------------
__global__ __launch_bounds__(256) void prep_final_kernel(
    const float* __restrict__ x, const float* __restrict__ root,
    const float* __restrict__ bias,
    const float* __restrict__ w1, const float* __restrict__ w2,
    const float* __restrict__ b2,
    _Float16* __restrict__ w2p, _Float16* __restrict__ w1p, _Float16* __restrict__ b2p,
    float* __restrict__ out)
{
    const int t = blockIdx.x * 256 + threadIdx.x;

    if (t < 131072) {
        int j = t & 7, lane = (t >> 3) & 63, ih = (t >> 9) & 1, c = t >> 10;
        w2p[t] = (_Float16)w2[c * 1024 + (ih * 16 + ((lane >> 5) << 3) + j) * 32 + (lane & 31)];
    } else if (t < 135168) {
        int u = t - 131072;
        int j = u & 7, lane = (u >> 3) & 63, kk = (u >> 9) & 1, r = u >> 10;
        w1p[u] = (_Float16)w1[(kk * 16 + ((lane >> 5) << 3) + j) * 128 + r * 32 + (lane & 31)];
    } else if (t < 136192) {
        int u = t - 135168;
        int j = u & 7, lane = (u >> 3) & 63, ih = u >> 9;
        b2p[u] = (_Float16)b2[(ih * 16 + ((lane >> 5) << 3) + j) * 32 + (lane & 31)];
    }

    int n = t >> 5, o = t & 31;
    float acc = bias[o];
    const float* xr = x + (n << 5);
#pragma unroll
    for (int i = 0; i < 32; ++i)
        acc = fmaf(xr[i], root[(i << 5) + o], acc);
    out[t] = acc;
}

// ---------------- launch 2: edge kernel (LDS-free, reg-resident h) ----------------
// 128 thr = 2 waves x 128 edges (4 groups of 32) = 256 edges/block, 1563 blocks.
__global__ __launch_bounds__(128, 1) void edge_kernel(
    const float*    __restrict__ x,
    const int*      __restrict__ ei,
    const float*    __restrict__ ea,
    const float*    __restrict__ b1,
    const _Float16* __restrict__ w2p,
    const _Float16* __restrict__ w1p,
    const _Float16* __restrict__ b2p,
    float* __restrict__ out)
{
    const int t    = threadIdx.x;
    const int w    = t >> 6;
    const int lane = t & 63;
    const int l    = lane & 31;
    const int half = lane >> 5;

    const int  ebraw = blockIdx.x * 256 + w * 128;
    const bool live  = (ebraw + 128) <= EE;        // wave-uniform; 128 | EE
    const int  ebw   = live ? ebraw : (EE - 128);

    union u8h { f16x8 v; __half2 h2[4]; };

    // ---- w2 B-columns read DIRECTLY from global (L2-resident, 256 KB) ----
    const f16x8* __restrict__ w2f = (const f16x8*)w2p;

    f16x8 BA[2], BB[2], BC[2], BD[2];              // 4-deep column buffers
    auto loadCol = [&](int j, f16x8 (&B)[2]) {
        const f16x8* p = w2f + (size_t)j * 128 + lane;
        B[0] = p[0];
        B[1] = p[64];
    };
    loadCol(0, BA); loadCol(1, BB); loadCol(2, BC); loadCol(3, BD);

    // ---- persistent edge-attr fragments (fp16), 4 groups; read ONCE (32 VGPR) ----
    u8h eaf[4][2];
#pragma unroll
    for (int g = 0; g < 4; ++g)
#pragma unroll
        for (int kk = 0; kk < 2; ++kk) {
            const float* p = ea + (size_t)(ebw + g * 32 + l) * 32 + kk * 16 + half * 8;
            float4 a0 = *(const float4*)p;
            float4 a1 = *(const float4*)(p + 4);
            eaf[g][kk].h2[0] = __float22half2_rn(make_float2(a0.x, a0.y));
            eaf[g][kk].h2[1] = __float22half2_rn(make_float2(a0.z, a0.w));
            eaf[g][kk].h2[2] = __float22half2_rn(make_float2(a1.x, a1.y));
            eaf[g][kk].h2[3] = __float22half2_rn(make_float2(a1.z, a1.w));
        }

    // ---- gather xs rows (fp16 pairs) for 4 groups: 32 VGPRs ----
    __half2 xs[4][8];
#pragma unroll
    for (int g = 0; g < 4; ++g) {
        int s = ei[ebw + g * 32 + l];
#pragma unroll
        for (int ih = 0; ih < 2; ++ih) {
            float4 a0 = *(const float4*)(x + s * 32 + ih * 16 + half * 8);
            float4 a1 = *(const float4*)(x + s * 32 + ih * 16 + half * 8 + 4);
            xs[g][ih*4+0] = __float22half2_rn(make_float2(a0.x, a0.y));
            xs[g][ih*4+1] = __float22half2_rn(make_float2(a0.z, a0.w));
            xs[g][ih*4+2] = __float22half2_rn(make_float2(a1.x, a1.y));
            xs[g][ih*4+3] = __float22half2_rn(make_float2(a1.z, a1.w));
        }
    }

    f32x16 acc[4];
#pragma unroll
    for (int g = 0; g < 4; ++g)
#pragma unroll
        for (int i = 0; i < 16; ++i) acc[g][i] = 0.f;

    // h slice own-half pairs: hpk[g][jj] = channels (base(jj)+4*half, +1),
    // base(jj) = (2jj&3) + ((2jj>>2)<<3). 32 VGPRs, rewritten per slice.
    __half2 hpk[4][8];

    auto phase1 = [&](int r) {
        f16x8 w1f0 = *(const f16x8*)(w1p + ((r * 2 + 0) * 64 + lane) * 8);
        f16x8 w1f1 = *(const f16x8*)(w1p + ((r * 2 + 1) * 64 + lane) * 8);
#pragma unroll
        for (int g = 0; g < 4; ++g) {
            f32x16 h;
#pragma unroll
            for (int i = 0; i < 16; ++i) h[i] = 0.f;
            h = __builtin_amdgcn_mfma_f32_32x32x16_f16(w1f0, eaf[g][0].v, h, 0, 0, 0);
            h = __builtin_amdgcn_mfma_f32_32x32x16_f16(w1f1, eaf[g][1].v, h, 0, 0, 0);
#pragma unroll
            for (int jj = 0; jj < 8; ++jj) {
                int i0 = 2 * jj;
                int r0 = (i0 & 3) + ((i0 >> 2) << 3) + (half << 2);  // verified C/D map
                hpk[g][jj] = __float22half2_rn(make_float2(
                    fmaxf(h[i0]     + b1[r * 32 + r0],     0.f),
                    fmaxf(h[i0 + 1] + b1[r * 32 + r0 + 1], 0.f)));
            }
        }
    };

    // swap cache: Ac = half0 rows {base,base+1}, Yc = half1 rows {+4,+5}
    __half2 Ac[4][2], Yc[4][2];

    // one column: d = lane-uniform channel scalar per group, 8 MFMAs
    auto colMFMA = [&](const __half2 (&C)[4][2], int dd, bool hi,
                       const f16x8 (&B)[2]) {
        __half2 d[4];
#pragma unroll
        for (int g = 0; g < 4; ++g)
            d[g] = __half2half2(hi ? __high2half(C[g][dd]) : __low2half(C[g][dd]));
#pragma unroll
        for (int ih = 0; ih < 2; ++ih) {
            f16x8 bfr = B[ih];
#pragma unroll
            for (int g = 0; g < 4; ++g) {
                u8h A;
#pragma unroll
                for (int p = 0; p < 4; ++p)
                    A.h2[p] = __hmul2(d[g], xs[g][ih * 4 + p]);   // v_pk_mul_f16
                acc[g] = __builtin_amdgcn_mfma_f32_32x32x16_f16(A.v, bfr, acc[g], 0, 0, 0);
            }
        }
    };

    // ---- main loop: R17 skeleton; cols linear, 3-col prefetch distance.
    // Channel cs = q*4+cl: even q -> Ac[jj-local cl>>1], odd q -> Yc;
    // hi = cl&1. Swap at even q fills Ac/Yc for jj = {q, q+1}.
    // Max overread col 131 lands in w1p/b2p region (valid, unused).
#pragma unroll 1
    for (int r = 0; r < 4; ++r) {
        phase1(r);
#pragma unroll
        for (int q = 0; q < 8; ++q) {
            const int j = r * 32 + q * 4;
            if ((q & 1) == 0) {
#pragma unroll
                for (int g = 0; g < 4; ++g)
#pragma unroll
                    for (int dd = 0; dd < 2; ++dd) {
                        unsigned a, y;
                        swapHalves(__builtin_bit_cast(unsigned, hpk[g][q + dd]),
                                   half, a, y);
                        Ac[g][dd] = __builtin_bit_cast(__half2, a);
                        Yc[g][dd] = __builtin_bit_cast(__half2, y);
                    }
                colMFMA(Ac, 0, false, BA); loadCol(j + 4, BA);
                colMFMA(Ac, 0, true,  BB); loadCol(j + 5, BB);
                colMFMA(Ac, 1, false, BC); loadCol(j + 6, BC);
                colMFMA(Ac, 1, true,  BD); loadCol(j + 7, BD);
            } else {
                colMFMA(Yc, 0, false, BA); loadCol(j + 4, BA);
                colMFMA(Yc, 0, true,  BB); loadCol(j + 5, BB);
                colMFMA(Yc, 1, false, BC); loadCol(j + 6, BC);
                colMFMA(Yc, 1, true,  BD); loadCol(j + 7, BD);
            }
        }
    }

    // ---- b2 contribution: extra K-step with h == 1 (A-fragment = xs) ----
#pragma unroll
    for (int ih = 0; ih < 2; ++ih) {
        f16x8 bfr = *(const f16x8*)(b2p + (ih * 64 + lane) * 8);
#pragma unroll
        for (int g = 0; g < 4; ++g) {
            u8h A;
#pragma unroll
            for (int p = 0; p < 4; ++p) A.h2[p] = xs[g][ih * 4 + p];
            acc[g] = __builtin_amdgcn_mfma_f32_32x32x16_f16(A.v, bfr, acc[g], 0, 0, 0);
        }
    }

    // ---- scatter-add into out (base written by launch 1) ----
    if (live) {
#pragma unroll
        for (int g = 0; g < 4; ++g)
#pragma unroll
            for (int i = 0; i < 16; ++i) {
                int el = (i & 3) + ((i >> 2) << 3) + (half << 2);
                atomicAdd(out + (size_t)ei[EE + ebw + g * 32 + el] * 32 + l, acc[g][i]);
            }
    }
}

extern "C" void kernel_launch(void* const* d_in, const int* in_sizes, int n_in,
                              void* d_out, int out_size, void* d_ws, size_t ws_size,
                              hipStream_t stream) {
    const float* x    = (const float*)d_in[0];
    const int*   ei   = (const int*)  d_in[1];
    const float* ea   = (const float*)d_in[2];
    const float* w1   = (const float*)d_in[3];
    const float* b1   = (const float*)d_in[4];
    const float* w2   = (const float*)d_in[5];
    const float* b2   = (const float*)d_in[6];
    const float* root = (const float*)d_in[7];
    const float* bias = (const float*)d_in[8];
    float* out = (float*)d_out;

    _Float16* w2p = (_Float16*)d_ws;                      // 262144 B
    _Float16* w1p = (_Float16*)((char*)d_ws + 262144);    //   8192 B
    _Float16* b2p = (_Float16*)((char*)d_ws + 270336);    //   2048 B
    // (edge kernel overread headroom: may touch up to ~270.4 KB of d_ws)

    prep_final_kernel<<<(NN * 32) / 256, 256, 0, stream>>>(
        x, root, bias, w1, w2, b2, w2p, w1p, b2p, out);

    edge_kernel<<<(EE + 255) / 256, 128, 0, stream>>>(
        x, ei, ea, b1, w2p, w1p, b2p, out);
}